// Round 14
// baseline (69.258 us; speedup 1.0000x reference)
//
#include <hip/hip_runtime.h>
#include <hip/hip_bf16.h>

typedef __attribute__((ext_vector_type(8))) short bf16x8;
typedef __attribute__((ext_vector_type(4))) short s16x4;
typedef __attribute__((ext_vector_type(4))) float f32x4;

__device__ __forceinline__ short f2b(float f) {
    __hip_bfloat16 h = __float2bfloat16(f);   // RNE
    return __builtin_bit_cast(short, h);
}

#define NPH 16
#define KC  256     // floats per row per phase (1 KB f32 / 512 B bf16)

// Kernel 1: x f32 -> bf16, and y2 = 2*(x @ A^T) as bf16.
__global__ void prep_kernel(const float* __restrict__ x,
                            const float* __restrict__ A,
                            ushort* __restrict__ xb,     // [64][4096] bf16
                            ushort* __restrict__ yb) {   // [64][64] bf16
    const int tid = threadIdx.x, bid = blockIdx.x;

    const int gid = bid * 256 + tid;
    if (gid < 65536) {
        float4 v = ((const float4*)x)[gid];
        ushort4 s;
        s.x = (ushort)f2b(v.x); s.y = (ushort)f2b(v.y);
        s.z = (ushort)f2b(v.z); s.w = (ushort)f2b(v.w);
        ((ushort4*)xb)[gid] = s;
    }

    const int wave = tid >> 6, lane = tid & 63;
    const int idx = bid * 4 + wave;          // 0..4095
    const int t = idx >> 6, r = idx & 63;
    const float4* xr = (const float4*)(x + (size_t)t * 4096);
    const float4* ar = (const float4*)(A + (size_t)r * 4096);
    float s = 0.f;
    #pragma unroll
    for (int i = 0; i < 16; ++i) {
        float4 a = xr[i * 64 + lane];
        float4 b = ar[i * 64 + lane];
        s += a.x * b.x + a.y * b.y + a.z * b.z + a.w * b.w;
    }
    #pragma unroll
    for (int off = 32; off; off >>= 1) s += __shfl_xor(s, off, 64);
    if (lane == 0) yb[idx] = (ushort)f2b(2.0f * s);
}

// Kernel 2: out[64][16384] = x@W^T + y2@B^T.
// 256 blocks x 512 threads (1 block/CU). Block owns 64 W-rows (contiguous
// 1 MB). R13 structure (proven: 65 us) + ONE change: streamer DISTANCE-2
// prefetch via two named reg banks. Loads for phase p are issued ~2 phases
// (~12k cy) ahead, so the ~900cy HBM latency no longer sits serially at
// each phase start; in-order vmcnt means CVTW(A) waits at vmcnt(16),
// leaving bank B's 16 loads in flight across the barrier.
__global__ void __launch_bounds__(512)
lora_gemm(const float* __restrict__ W,      // [16384][4096]
          const float* __restrict__ Bm,     // [16384][64]
          const ushort* __restrict__ xb,    // [64][4096] bf16
          const ushort* __restrict__ yb,    // [64][64] bf16
          float* __restrict__ out) {        // [64][16384]
    __shared__ ushort buf[2][64 * KC];      // 2 x 32 KB

    const int tid  = threadIdx.x;
    const int w    = tid >> 6;              // wave 0..7
    const int lane = tid & 63;
    const int j0   = blockIdx.x << 6;       // 64 W-rows / out-cols per block

    if (w >= 4) {
        // ---------------- STREAMER (waves 4..7): rows s*16 .. s*16+15 ----
        const int s = w - 4;
        f32x4 bkA[16], bkB[16];             // distance-2 banks (static idx)

        #define ISSUE(bk, p)                                                \
            { _Pragma("unroll")                                             \
              for (int i = 0; i < 16; ++i) {                                \
                  const float* src = W + (size_t)(j0 + s * 16 + i) * 4096   \
                                       + (p) * KC + lane * 4;               \
                  bk[i] = *(const f32x4*)src;                               \
              } }

        #define CVTW(bk, b)                                                 \
            { char* dst = (char*)&buf[b][0];                                \
              _Pragma("unroll")                                             \
              for (int i = 0; i < 16; ++i) {                                \
                  const int q = s * 16 + i;                                 \
                  s16x4 v;                                                  \
                  v[0] = f2b(bk[i][0]); v[1] = f2b(bk[i][1]);               \
                  v[2] = f2b(bk[i][2]); v[3] = f2b(bk[i][3]);               \
                  *(s16x4*)(dst + q * 512 + ((lane * 8) ^ ((q & 7) << 4)))  \
                      = v;                                                  \
              } }

        #define LGKM_BAR()                                                  \
            asm volatile("s_waitcnt lgkmcnt(0)" ::: "memory");              \
            __builtin_amdgcn_s_barrier();

        ISSUE(bkA, 0);
        ISSUE(bkB, 1);
        #pragma unroll
        for (int p = 0; p < NPH; p += 2) {
            CVTW(bkA, 0);                    // waits vmcnt(16): B in flight
            LGKM_BAR();                      // fill p visible
            if (p + 2 < NPH) ISSUE(bkA, p + 2);
            CVTW(bkB, 1);                    // waits vmcnt(16): A in flight
            LGKM_BAR();                      // fill p+1 visible
            if (p + 3 < NPH) ISSUE(bkB, p + 3);
        }
        #undef ISSUE
        #undef CVTW
        #undef LGKM_BAR
        return;
    }

    // ---------------- CONSUMER (waves 0..3): tokens w*16..w*16+15 --------
    const int c  = lane & 15;               // token row / D-col index
    const int kg = lane >> 4;               // k-group, offset kg*8
    const ushort* xrow = xb + (size_t)(w * 16 + c) * 4096 + kg * 8;

    f32x4 acc[4];
    #pragma unroll
    for (int n = 0; n < 4; ++n) acc[n] = f32x4{0.f, 0.f, 0.f, 0.f};

    __builtin_amdgcn_s_barrier();           // B0: panel 0 ready

    for (int p = 0; p < NPH; ++p) {
        const char* lb = (const char*)&buf[p & 1][0];
        #pragma unroll
        for (int sl = 0; sl < 8; ++sl) {
            bf16x8 aa = *(const bf16x8*)(xrow + p * KC + sl * 32);
            #pragma unroll
            for (int n = 0; n < 4; ++n) {
                const int q = n * 16 + c;    // W-row within block = D col
                bf16x8 bb = *(const bf16x8*)(lb + q * 512
                    + ((sl * 64 + kg * 16) ^ ((q & 7) << 4)));
                acc[n] = __builtin_amdgcn_mfma_f32_16x16x32_bf16(
                    aa, bb, acc[n], 0, 0, 0);
            }
        }
        if (p + 1 < NPH) {
            asm volatile("s_waitcnt lgkmcnt(0)" ::: "memory");
            __builtin_amdgcn_s_barrier();    // B(p+1)
        }
    }

    // lora tail: 2 K-steps over r=64 per col-subtile
    {
        const ushort* y0 = yb + (size_t)(w * 16 + c) * 64 + kg * 8;
        #pragma unroll
        for (int n = 0; n < 4; ++n) {
            const float* br = Bm + (size_t)(j0 + n * 16 + c) * 64 + kg * 8;
            #pragma unroll
            for (int k = 0; k < 64; k += 32) {
                f32x4 w0 = *(const f32x4*)(br + k);
                f32x4 w1 = *(const f32x4*)(br + k + 4);
                bf16x8 bb;
                bb[0] = f2b(w0[0]); bb[1] = f2b(w0[1]);
                bb[2] = f2b(w0[2]); bb[3] = f2b(w0[3]);
                bb[4] = f2b(w1[0]); bb[5] = f2b(w1[1]);
                bb[6] = f2b(w1[2]); bb[7] = f2b(w1[3]);
                bf16x8 aa = *(const bf16x8*)(y0 + k);
                acc[n] = __builtin_amdgcn_mfma_f32_16x16x32_bf16(
                    aa, bb, acc[n], 0, 0, 0);
            }
        }
    }

    // store: token row = w*16 + kg*4 + r, col = j0 + n*16 + c
    #pragma unroll
    for (int n = 0; n < 4; ++n) {
        float* op = out + j0 + n * 16 + c;
        #pragma unroll
        for (int r = 0; r < 4; ++r)
            op[(size_t)(w * 16 + kg * 4 + r) * 16384] = acc[n][r];
    }
}

extern "C" void kernel_launch(void* const* d_in, const int* in_sizes, int n_in,
                              void* d_out, int out_size, void* d_ws, size_t ws_size,
                              hipStream_t stream) {
    const float* x  = (const float*)d_in[0];
    const float* W  = (const float*)d_in[1];
    const float* A  = (const float*)d_in[2];
    const float* Bm = (const float*)d_in[3];
    float* out = (float*)d_out;

    ushort* xb = (ushort*)d_ws;                          // 64*4096*2 = 524288 B
    ushort* yb = (ushort*)((char*)d_ws + 524288);        // 64*64*2   = 8192 B

    prep_kernel<<<1024, 256, 0, stream>>>(x, A, xb, yb);
    lora_gemm<<<256, 512, 0, stream>>>(W, Bm, xb, yb, out);
}

// Round 15
// 64.909 us; speedup vs baseline: 1.0670x; 1.0670x over previous
//
#include <hip/hip_runtime.h>
#include <hip/hip_bf16.h>

typedef __attribute__((ext_vector_type(8))) short bf16x8;
typedef __attribute__((ext_vector_type(4))) float f32x4;

__device__ __forceinline__ short f2b(float f) {
    __hip_bfloat16 h = __float2bfloat16(f);   // RNE
    return __builtin_bit_cast(short, h);
}

#define NPH 32
#define KC  128     // floats per row per phase (512 B f32)

// Kernel 1: x f32 -> bf16, and y2 = 2*(x @ A^T) as bf16.
__global__ void prep_kernel(const float* __restrict__ x,
                            const float* __restrict__ A,
                            ushort* __restrict__ xb,     // [64][4096] bf16
                            ushort* __restrict__ yb) {   // [64][64] bf16
    const int tid = threadIdx.x, bid = blockIdx.x;

    const int gid = bid * 256 + tid;
    if (gid < 65536) {
        float4 v = ((const float4*)x)[gid];
        ushort4 s;
        s.x = (ushort)f2b(v.x); s.y = (ushort)f2b(v.y);
        s.z = (ushort)f2b(v.z); s.w = (ushort)f2b(v.w);
        ((ushort4*)xb)[gid] = s;
    }

    const int wave = tid >> 6, lane = tid & 63;
    const int idx = bid * 4 + wave;          // 0..4095
    const int t = idx >> 6, r = idx & 63;
    const float4* xr = (const float4*)(x + (size_t)t * 4096);
    const float4* ar = (const float4*)(A + (size_t)r * 4096);
    float s = 0.f;
    #pragma unroll
    for (int i = 0; i < 16; ++i) {
        float4 a = xr[i * 64 + lane];
        float4 b = ar[i * 64 + lane];
        s += a.x * b.x + a.y * b.y + a.z * b.z + a.w * b.w;
    }
    #pragma unroll
    for (int off = 32; off; off >>= 1) s += __shfl_xor(s, off, 64);
    if (lane == 0) yb[idx] = (ushort)f2b(2.0f * s);
}

// Kernel 2: out[64][16384] = x@W^T + y2@B^T.
// 256 blocks x 512 threads (1 block/CU, forced by 96 KB LDS). Block owns 64
// W-rows (contiguous 1 MB). R13's traffic shape (the proven lever: x read
// once per block) with the staging redone as:
//   - global_load_lds (zero VGPR, no streamer cvt),
//   - TRIPLE-buffered f32 LDS (3 x 32 KB), KC=128, 32 phases,
//   - counted vmcnt(8) per phase -- NEVER 0 in the loop (T4): phase p+2's
//     loads are issued ~2 phase-times (~3000 cy) before consumption, so the
//     ~900 cy HBM latency is fully covered and 16 loads/wave stay in flight
//     across every barrier. Triple buffer makes depth-2 race-free:
//     issue(p+2) targets buf[(p+2)%3] == buf[(p-1)%3], which consumers
//     finished before barrier p.
//   - swizzle via PRE-SWIZZLED GLOBAL SOURCE (rule #21: linear LDS dest +
//     inverse-swz source + swz read). One gload_lds covers 2 rows (lane
//     0..31 -> row q, 32..63 -> row q+1; per-lane source addr is free).
//   - consumers cvt f32->bf16 themselves (~400 cy/phase, hidden under the
//     ~1560 cy phase BW budget; scalar f2b so compiler emits cvt_pk).
__global__ void __launch_bounds__(512)
lora_gemm(const float* __restrict__ W,      // [16384][4096]
          const float* __restrict__ Bm,     // [16384][64]
          const ushort* __restrict__ xb,    // [64][4096] bf16
          const ushort* __restrict__ yb,    // [64][64] bf16
          float* __restrict__ out) {        // [64][16384]
    __shared__ char buf[3][64 * 512];       // 3 x 32 KB f32 panels

    const int tid  = threadIdx.x;
    const int w    = tid >> 6;              // wave 0..7
    const int lane = tid & 63;
    const int j0   = blockIdx.x << 6;       // 64 W-rows / out-cols per block

    if (w >= 4) {
        // ------- STREAMER (waves 4..7): rows s*16 .. s*16+15 -------------
        const int s = w - 4;
        // per issue: 8 gload_lds, each staging 2 rows x 512 B.
        auto issue = [&](int p) {
            char* dst = &buf[p % 3][0];
            #pragma unroll
            for (int i = 0; i < 8; ++i) {
                const int qa = s * 16 + i * 2;          // first of 2 rows
                const int q  = qa + (lane >> 5);        // this lane's row
                const int b  = (lane & 31) * 16;        // byte in 512B chunk
                const char* src = (const char*)(W + (size_t)(j0 + q) * 4096
                                                + (size_t)p * KC)
                                  + (b ^ ((q & 7) << 4));   // inverse swz
                __builtin_amdgcn_global_load_lds(
                    (const uint32_t*)src,
                    (uint32_t*)(dst + qa * 512), 16, 0, 0);
            }
        };

        issue(0);
        issue(1);
        for (int p = 0; p < NPH - 1; ++p) {
            asm volatile("s_waitcnt vmcnt(8)" ::: "memory");  // p landed,
            __builtin_amdgcn_s_barrier();                     // p+1 in flight
            if (p + 2 < NPH) issue(p + 2);
        }
        asm volatile("s_waitcnt vmcnt(0)" ::: "memory");      // last phase
        __builtin_amdgcn_s_barrier();
        return;
    }

    // ------- CONSUMER (waves 0..3): tokens w*16..w*16+15 -----------------
    const int c  = lane & 15;               // token row / D-col index
    const int kg = lane >> 4;               // k-group, offset kg*8
    const ushort* xrow = xb + (size_t)(w * 16 + c) * 4096 + kg * 8;

    f32x4 acc[4];
    #pragma unroll
    for (int n = 0; n < 4; ++n) acc[n] = f32x4{0.f, 0.f, 0.f, 0.f};

    for (int p = 0; p < NPH; ++p) {
        __builtin_amdgcn_s_barrier();       // B_p: buf[p%3] ready
        const char* lb = &buf[p % 3][0];
        #pragma unroll
        for (int sl = 0; sl < 4; ++sl) {
            bf16x8 aa = *(const bf16x8*)(xrow + p * KC + sl * 32);
            #pragma unroll
            for (int n = 0; n < 4; ++n) {
                const int q   = n * 16 + c; // W-row within block = D col
                const int swz = (q & 7) << 4;
                const char* base = lb + q * 512;
                f32x4 w0 = *(const f32x4*)(base + ((sl * 128 + kg * 32) ^ swz));
                f32x4 w1 = *(const f32x4*)(base + ((sl * 128 + kg * 32 + 16) ^ swz));
                bf16x8 bb;
                bb[0] = f2b(w0[0]); bb[1] = f2b(w0[1]);
                bb[2] = f2b(w0[2]); bb[3] = f2b(w0[3]);
                bb[4] = f2b(w1[0]); bb[5] = f2b(w1[1]);
                bb[6] = f2b(w1[2]); bb[7] = f2b(w1[3]);
                acc[n] = __builtin_amdgcn_mfma_f32_16x16x32_bf16(
                    aa, bb, acc[n], 0, 0, 0);
            }
        }
    }

    // lora tail: 2 K-steps over r=64 per col-subtile
    {
        const ushort* y0 = yb + (size_t)(w * 16 + c) * 64 + kg * 8;
        #pragma unroll
        for (int n = 0; n < 4; ++n) {
            const float* br = Bm + (size_t)(j0 + n * 16 + c) * 64 + kg * 8;
            #pragma unroll
            for (int k = 0; k < 64; k += 32) {
                f32x4 w0 = *(const f32x4*)(br + k);
                f32x4 w1 = *(const f32x4*)(br + k + 4);
                bf16x8 bb;
                bb[0] = f2b(w0[0]); bb[1] = f2b(w0[1]);
                bb[2] = f2b(w0[2]); bb[3] = f2b(w0[3]);
                bb[4] = f2b(w1[0]); bb[5] = f2b(w1[1]);
                bb[6] = f2b(w1[2]); bb[7] = f2b(w1[3]);
                bf16x8 aa = *(const bf16x8*)(y0 + k);
                acc[n] = __builtin_amdgcn_mfma_f32_16x16x32_bf16(
                    aa, bb, acc[n], 0, 0, 0);
            }
        }
    }

    // store: token row = w*16 + kg*4 + r, col = j0 + n*16 + c
    #pragma unroll
    for (int n = 0; n < 4; ++n) {
        float* op = out + j0 + n * 16 + c;
        #pragma unroll
        for (int r = 0; r < 4; ++r)
            op[(size_t)(w * 16 + kg * 4 + r) * 16384] = acc[n][r];
    }
}

extern "C" void kernel_launch(void* const* d_in, const int* in_sizes, int n_in,
                              void* d_out, int out_size, void* d_ws, size_t ws_size,
                              hipStream_t stream) {
    const float* x  = (const float*)d_in[0];
    const float* W  = (const float*)d_in[1];
    const float* A  = (const float*)d_in[2];
    const float* Bm = (const float*)d_in[3];
    float* out = (float*)d_out;

    ushort* xb = (ushort*)d_ws;                          // 64*4096*2 = 524288 B
    ushort* yb = (ushort*)((char*)d_ws + 524288);        // 64*64*2   = 8192 B

    prep_kernel<<<1024, 256, 0, stream>>>(x, A, xb, yb);
    lora_gemm<<<256, 512, 0, stream>>>(W, Bm, xb, yb, out);
}

// Round 16
// 63.919 us; speedup vs baseline: 1.0835x; 1.0155x over previous
//
#include <hip/hip_runtime.h>
#include <hip/hip_bf16.h>

typedef __attribute__((ext_vector_type(8))) short bf16x8;
typedef __attribute__((ext_vector_type(4))) float f32x4;

__device__ __forceinline__ short f2b(float f) {
    __hip_bfloat16 h = __float2bfloat16(f);   // RNE
    return __builtin_bit_cast(short, h);
}

#define NPH 32
#define KC  128     // floats per row per phase (512 B f32)

// Kernel 1: x f32 -> bf16, and y2 = 2*(x @ A^T) as bf16.
__global__ void prep_kernel(const float* __restrict__ x,
                            const float* __restrict__ A,
                            ushort* __restrict__ xb,     // [64][4096] bf16
                            ushort* __restrict__ yb) {   // [64][64] bf16
    const int tid = threadIdx.x, bid = blockIdx.x;

    const int gid = bid * 256 + tid;
    if (gid < 65536) {
        float4 v = ((const float4*)x)[gid];
        ushort4 s;
        s.x = (ushort)f2b(v.x); s.y = (ushort)f2b(v.y);
        s.z = (ushort)f2b(v.z); s.w = (ushort)f2b(v.w);
        ((ushort4*)xb)[gid] = s;
    }

    const int wave = tid >> 6, lane = tid & 63;
    const int idx = bid * 4 + wave;          // 0..4095
    const int t = idx >> 6, r = idx & 63;
    const float4* xr = (const float4*)(x + (size_t)t * 4096);
    const float4* ar = (const float4*)(A + (size_t)r * 4096);
    float s = 0.f;
    #pragma unroll
    for (int i = 0; i < 16; ++i) {
        float4 a = xr[i * 64 + lane];
        float4 b = ar[i * 64 + lane];
        s += a.x * b.x + a.y * b.y + a.z * b.z + a.w * b.w;
    }
    #pragma unroll
    for (int off = 32; off; off >>= 1) s += __shfl_xor(s, off, 64);
    if (lane == 0) yb[idx] = (ushort)f2b(2.0f * s);
}

// Kernel 2: out[64][16384] = x@W^T + y2@B^T.
// R15 structure (proven 64.9 us) + ONE change: QUAD-buffered LDS -> prefetch
// depth 3. During consumer phase p, streamer loads for p+1, p+2, p+3 are all
// in flight (24/wave, 96/CU vs R15's 16/64); every wait leaves 16 outstanding
// (vs 8). Targets the one remaining delta vs the 6.6 TB/s wread probe: MLP
// (wread ran 128 requests/CU). Buffer (p+3)%4 is written only after barrier
// p, when consumers read p%4 and have finished (p+3)%4's previous contents.
__global__ void __launch_bounds__(512)
lora_gemm(const float* __restrict__ W,      // [16384][4096]
          const float* __restrict__ Bm,     // [16384][64]
          const ushort* __restrict__ xb,    // [64][4096] bf16
          const ushort* __restrict__ yb,    // [64][64] bf16
          float* __restrict__ out) {        // [64][16384]
    __shared__ char buf[4][64 * 512];       // 4 x 32 KB f32 panels

    const int tid  = threadIdx.x;
    const int w    = tid >> 6;              // wave 0..7
    const int lane = tid & 63;
    const int j0   = blockIdx.x << 6;       // 64 W-rows / out-cols per block

    if (w >= 4) {
        // ------- STREAMER (waves 4..7): rows s*16 .. s*16+15 -------------
        const int s = w - 4;
        // per issue: 8 gload_lds, each staging 2 rows x 512 B.
        auto issue = [&](int p) {
            char* dst = &buf[p & 3][0];
            #pragma unroll
            for (int i = 0; i < 8; ++i) {
                const int qa = s * 16 + i * 2;          // first of 2 rows
                const int q  = qa + (lane >> 5);        // this lane's row
                const int b  = (lane & 31) * 16;        // byte in 512B chunk
                const char* src = (const char*)(W + (size_t)(j0 + q) * 4096
                                                + (size_t)p * KC)
                                  + (b ^ ((q & 7) << 4));   // inverse swz
                __builtin_amdgcn_global_load_lds(
                    (const uint32_t*)src,
                    (uint32_t*)(dst + qa * 512), 16, 0, 0);
            }
        };

        issue(0);
        issue(1);
        issue(2);
        for (int p = 0; p < NPH - 2; ++p) {
            // phase p landed; p+1, p+2 stay in flight (16 outstanding)
            asm volatile("s_waitcnt vmcnt(16)" ::: "memory");
            __builtin_amdgcn_s_barrier();
            if (p + 3 < NPH) issue(p + 3);   // depth-3: 24 in flight
        }
        asm volatile("s_waitcnt vmcnt(8)" ::: "memory");   // p = NPH-2
        __builtin_amdgcn_s_barrier();
        asm volatile("s_waitcnt vmcnt(0)" ::: "memory");   // p = NPH-1
        __builtin_amdgcn_s_barrier();
        return;
    }

    // ------- CONSUMER (waves 0..3): tokens w*16..w*16+15 -----------------
    const int c  = lane & 15;               // token row / D-col index
    const int kg = lane >> 4;               // k-group, offset kg*8
    const ushort* xrow = xb + (size_t)(w * 16 + c) * 4096 + kg * 8;

    f32x4 acc[4];
    #pragma unroll
    for (int n = 0; n < 4; ++n) acc[n] = f32x4{0.f, 0.f, 0.f, 0.f};

    for (int p = 0; p < NPH; ++p) {
        __builtin_amdgcn_s_barrier();       // B_p: buf[p&3] ready
        const char* lb = &buf[p & 3][0];
        #pragma unroll
        for (int sl = 0; sl < 4; ++sl) {
            bf16x8 aa = *(const bf16x8*)(xrow + p * KC + sl * 32);
            #pragma unroll
            for (int n = 0; n < 4; ++n) {
                const int q   = n * 16 + c; // W-row within block = D col
                const int swz = (q & 7) << 4;
                const char* base = lb + q * 512;
                f32x4 w0 = *(const f32x4*)(base + ((sl * 128 + kg * 32) ^ swz));
                f32x4 w1 = *(const f32x4*)(base + ((sl * 128 + kg * 32 + 16) ^ swz));
                bf16x8 bb;
                bb[0] = f2b(w0[0]); bb[1] = f2b(w0[1]);
                bb[2] = f2b(w0[2]); bb[3] = f2b(w0[3]);
                bb[4] = f2b(w1[0]); bb[5] = f2b(w1[1]);
                bb[6] = f2b(w1[2]); bb[7] = f2b(w1[3]);
                acc[n] = __builtin_amdgcn_mfma_f32_16x16x32_bf16(
                    aa, bb, acc[n], 0, 0, 0);
            }
        }
    }

    // lora tail: 2 K-steps over r=64 per col-subtile
    {
        const ushort* y0 = yb + (size_t)(w * 16 + c) * 64 + kg * 8;
        #pragma unroll
        for (int n = 0; n < 4; ++n) {
            const float* br = Bm + (size_t)(j0 + n * 16 + c) * 64 + kg * 8;
            #pragma unroll
            for (int k = 0; k < 64; k += 32) {
                f32x4 w0 = *(const f32x4*)(br + k);
                f32x4 w1 = *(const f32x4*)(br + k + 4);
                bf16x8 bb;
                bb[0] = f2b(w0[0]); bb[1] = f2b(w0[1]);
                bb[2] = f2b(w0[2]); bb[3] = f2b(w0[3]);
                bb[4] = f2b(w1[0]); bb[5] = f2b(w1[1]);
                bb[6] = f2b(w1[2]); bb[7] = f2b(w1[3]);
                bf16x8 aa = *(const bf16x8*)(y0 + k);
                acc[n] = __builtin_amdgcn_mfma_f32_16x16x32_bf16(
                    aa, bb, acc[n], 0, 0, 0);
            }
        }
    }

    // store: token row = w*16 + kg*4 + r, col = j0 + n*16 + c
    #pragma unroll
    for (int n = 0; n < 4; ++n) {
        float* op = out + j0 + n * 16 + c;
        #pragma unroll
        for (int r = 0; r < 4; ++r)
            op[(size_t)(w * 16 + kg * 4 + r) * 16384] = acc[n][r];
    }
}

extern "C" void kernel_launch(void* const* d_in, const int* in_sizes, int n_in,
                              void* d_out, int out_size, void* d_ws, size_t ws_size,
                              hipStream_t stream) {
    const float* x  = (const float*)d_in[0];
    const float* W  = (const float*)d_in[1];
    const float* A  = (const float*)d_in[2];
    const float* Bm = (const float*)d_in[3];
    float* out = (float*)d_out;

    ushort* xb = (ushort*)d_ws;                          // 64*4096*2 = 524288 B
    ushort* yb = (ushort*)((char*)d_ws + 524288);        // 64*64*2   = 8192 B

    prep_kernel<<<1024, 256, 0, stream>>>(x, A, xb, yb);
    lora_gemm<<<256, 512, 0, stream>>>(W, Bm, xb, yb, out);
}

// Round 17
// 58.584 us; speedup vs baseline: 1.1822x; 1.0911x over previous
//
#include <hip/hip_runtime.h>
#include <hip/hip_bf16.h>

typedef __attribute__((ext_vector_type(8))) short bf16x8;
typedef __attribute__((ext_vector_type(4))) float f32x4;

__device__ __forceinline__ short f2b(float f) {
    __hip_bfloat16 h = __float2bfloat16(f);   // RNE
    return __builtin_bit_cast(short, h);
}

#define NPH 32
#define KC  128     // floats per row per phase (512 B f32)

// Kernel 1: x f32 -> bf16, and y2 = 2*(x @ A^T) as bf16.
__global__ void prep_kernel(const float* __restrict__ x,
                            const float* __restrict__ A,
                            ushort* __restrict__ xb,     // [64][4096] bf16
                            ushort* __restrict__ yb) {   // [64][64] bf16
    const int tid = threadIdx.x, bid = blockIdx.x;

    const int gid = bid * 256 + tid;
    if (gid < 65536) {
        float4 v = ((const float4*)x)[gid];
        ushort4 s;
        s.x = (ushort)f2b(v.x); s.y = (ushort)f2b(v.y);
        s.z = (ushort)f2b(v.z); s.w = (ushort)f2b(v.w);
        ((ushort4*)xb)[gid] = s;
    }

    const int wave = tid >> 6, lane = tid & 63;
    const int idx = bid * 4 + wave;          // 0..4095
    const int t = idx >> 6, r = idx & 63;
    const float4* xr = (const float4*)(x + (size_t)t * 4096);
    const float4* ar = (const float4*)(A + (size_t)r * 4096);
    float s = 0.f;
    #pragma unroll
    for (int i = 0; i < 16; ++i) {
        float4 a = xr[i * 64 + lane];
        float4 b = ar[i * 64 + lane];
        s += a.x * b.x + a.y * b.y + a.z * b.z + a.w * b.w;
    }
    #pragma unroll
    for (int off = 32; off; off >>= 1) s += __shfl_xor(s, off, 64);
    if (lane == 0) yb[idx] = (ushort)f2b(2.0f * s);
}

// Kernel 2: out[64][16384] = x@W^T + y2@B^T.
// R16 structure (63.9 us proven) + ONE change: PER-BLOCK K-PHASE ROTATION.
// Mechanism: W rows are 16 KB apart; within a phase every block reads 512 B
// chunks at byte offset p*512 of each row -> address bits 9..13 are frozen
// to p chip-wide (blocks advance p in barrier-paced lockstep). HBM channel
// interleave lives in those bits: per instant only a channel subset is
// active (the measured 4.7 of 6.6 TB/s). Rotation p = (b + i) & 31 makes
// all 32 phase-classes (8 blocks each) active simultaneously -> uniform
// channel coverage. Buffers indexed by loop position i (not p); f32 acc
// order change is harmless (absmax 0.0625 << 0.224). R4's rotation null
// was in the 11%-HBM duty-cycle regime where this mechanism is invisible.
__global__ void __launch_bounds__(512)
lora_gemm(const float* __restrict__ W,      // [16384][4096]
          const float* __restrict__ Bm,     // [16384][64]
          const ushort* __restrict__ xb,    // [64][4096] bf16
          const ushort* __restrict__ yb,    // [64][64] bf16
          float* __restrict__ out) {        // [64][16384]
    __shared__ char buf[4][64 * 512];       // 4 x 32 KB f32 panels

    const int tid  = threadIdx.x;
    const int w    = tid >> 6;              // wave 0..7
    const int lane = tid & 63;
    const int j0   = blockIdx.x << 6;       // 64 W-rows / out-cols per block
    const int p0   = blockIdx.x & 31;       // phase rotation start

    if (w >= 4) {
        // ------- STREAMER (waves 4..7): rows s*16 .. s*16+15 -------------
        const int s = w - 4;
        // issue slot i: stages phase (p0+i)&31 into buf[i&3].
        auto issue = [&](int i) {
            const int p = (p0 + i) & 31;
            char* dst = &buf[i & 3][0];
            #pragma unroll
            for (int k = 0; k < 8; ++k) {
                const int qa = s * 16 + k * 2;          // first of 2 rows
                const int q  = qa + (lane >> 5);        // this lane's row
                const int b  = (lane & 31) * 16;        // byte in 512B chunk
                const char* src = (const char*)(W + (size_t)(j0 + q) * 4096
                                                + (size_t)p * KC)
                                  + (b ^ ((q & 7) << 4));   // inverse swz
                __builtin_amdgcn_global_load_lds(
                    (const uint32_t*)src,
                    (uint32_t*)(dst + qa * 512), 16, 0, 0);
            }
        };

        issue(0);
        issue(1);
        issue(2);
        for (int i = 0; i < NPH - 2; ++i) {
            // slot i landed; i+1, i+2 stay in flight (16 outstanding)
            asm volatile("s_waitcnt vmcnt(16)" ::: "memory");
            __builtin_amdgcn_s_barrier();
            if (i + 3 < NPH) issue(i + 3);   // depth-3: 24 in flight
        }
        asm volatile("s_waitcnt vmcnt(8)" ::: "memory");   // i = NPH-2
        __builtin_amdgcn_s_barrier();
        asm volatile("s_waitcnt vmcnt(0)" ::: "memory");   // i = NPH-1
        __builtin_amdgcn_s_barrier();
        return;
    }

    // ------- CONSUMER (waves 0..3): tokens w*16..w*16+15 -----------------
    const int c  = lane & 15;               // token row / D-col index
    const int kg = lane >> 4;               // k-group, offset kg*8
    const ushort* xrow = xb + (size_t)(w * 16 + c) * 4096 + kg * 8;

    f32x4 acc[4];
    #pragma unroll
    for (int n = 0; n < 4; ++n) acc[n] = f32x4{0.f, 0.f, 0.f, 0.f};

    for (int i = 0; i < NPH; ++i) {
        const int p = (p0 + i) & 31;
        __builtin_amdgcn_s_barrier();       // B_i: buf[i&3] ready
        const char* lb = &buf[i & 3][0];
        #pragma unroll
        for (int sl = 0; sl < 4; ++sl) {
            bf16x8 aa = *(const bf16x8*)(xrow + p * KC + sl * 32);
            #pragma unroll
            for (int n = 0; n < 4; ++n) {
                const int q   = n * 16 + c; // W-row within block = D col
                const int swz = (q & 7) << 4;
                const char* base = lb + q * 512;
                f32x4 w0 = *(const f32x4*)(base + ((sl * 128 + kg * 32) ^ swz));
                f32x4 w1 = *(const f32x4*)(base + ((sl * 128 + kg * 32 + 16) ^ swz));
                bf16x8 bb;
                bb[0] = f2b(w0[0]); bb[1] = f2b(w0[1]);
                bb[2] = f2b(w0[2]); bb[3] = f2b(w0[3]);
                bb[4] = f2b(w1[0]); bb[5] = f2b(w1[1]);
                bb[6] = f2b(w1[2]); bb[7] = f2b(w1[3]);
                acc[n] = __builtin_amdgcn_mfma_f32_16x16x32_bf16(
                    aa, bb, acc[n], 0, 0, 0);
            }
        }
    }

    // lora tail: 2 K-steps over r=64 per col-subtile
    {
        const ushort* y0 = yb + (size_t)(w * 16 + c) * 64 + kg * 8;
        #pragma unroll
        for (int n = 0; n < 4; ++n) {
            const float* br = Bm + (size_t)(j0 + n * 16 + c) * 64 + kg * 8;
            #pragma unroll
            for (int k = 0; k < 64; k += 32) {
                f32x4 w0 = *(const f32x4*)(br + k);
                f32x4 w1 = *(const f32x4*)(br + k + 4);
                bf16x8 bb;
                bb[0] = f2b(w0[0]); bb[1] = f2b(w0[1]);
                bb[2] = f2b(w0[2]); bb[3] = f2b(w0[3]);
                bb[4] = f2b(w1[0]); bb[5] = f2b(w1[1]);
                bb[6] = f2b(w1[2]); bb[7] = f2b(w1[3]);
                bf16x8 aa = *(const bf16x8*)(y0 + k);
                acc[n] = __builtin_amdgcn_mfma_f32_16x16x32_bf16(
                    aa, bb, acc[n], 0, 0, 0);
            }
        }
    }

    // store: token row = w*16 + kg*4 + r, col = j0 + n*16 + c
    #pragma unroll
    for (int n = 0; n < 4; ++n) {
        float* op = out + j0 + n * 16 + c;
        #pragma unroll
        for (int r = 0; r < 4; ++r)
            op[(size_t)(w * 16 + kg * 4 + r) * 16384] = acc[n][r];
    }
}

extern "C" void kernel_launch(void* const* d_in, const int* in_sizes, int n_in,
                              void* d_out, int out_size, void* d_ws, size_t ws_size,
                              hipStream_t stream) {
    const float* x  = (const float*)d_in[0];
    const float* W  = (const float*)d_in[1];
    const float* A  = (const float*)d_in[2];
    const float* Bm = (const float*)d_in[3];
    float* out = (float*)d_out;

    ushort* xb = (ushort*)d_ws;                          // 64*4096*2 = 524288 B
    ushort* yb = (ushort*)((char*)d_ws + 524288);        // 64*64*2   = 8192 B

    prep_kernel<<<1024, 256, 0, stream>>>(x, A, xb, yb);
    lora_gemm<<<256, 512, 0, stream>>>(W, Bm, xb, yb, out);
}